// Round 4
// baseline (46.879 us; speedup 1.0000x reference)
//
#include <hip/hip_runtime.h>
#include <math.h>

// B=1, N=4096 queries, F=4096 faces (fixed by reference setup_inputs).
#define N_Q 4096
#define N_F 4096
#define QPT 4                  // queries per thread (ILP + face-load amortization)
#define QBLK (256 * QPT)       // 1024 queries per block
#define FSPLIT 256             // 4 q-blocks x 256 f-splits = 1024 blocks (4/CU)
#define FT (N_F / FSPLIT)      // 16 faces per block
#define INV_2PI 0.15915494309189535f

// Fast atan2: 6-coeff odd minimax poly on [0,1] (max err ~1e-5 rad),
// v_rcp_f32 division, quadrant fixup via selects.
__device__ __forceinline__ float fast_atan2f(float y, float x) {
    const float pi   = 3.14159265358979f;
    const float pi_2 = 1.57079632679490f;
    float ax = fabsf(x), ay = fabsf(y);
    float mx = fmaxf(ax, ay), mn = fminf(ax, ay);
    float t = mn * __builtin_amdgcn_rcpf(mx);      // t in [0,1]
    t = (mx == 0.0f) ? 0.0f : t;                   // atan2(0,0) -> 0 guard
    float s = t * t;
    float p =              -0.0117212f;
    p = fmaf(p, s,  0.05265332f);
    p = fmaf(p, s, -0.11643287f);
    p = fmaf(p, s,  0.19354346f);
    p = fmaf(p, s, -0.33262347f);
    p = fmaf(p, s,  0.99997726f);
    float r = p * t;                               // atan(t) on [0, pi/4]
    r = (ay > ax) ? (pi_2 - r) : r;                // octant -> quadrant I
    r = (x < 0.0f) ? (pi - r) : r;                 // quadrant II
    return copysignf(r, y);                        // lower half-plane
}

__device__ __forceinline__ float pair_term(
    float qx, float qy, float qz,
    float v0, float v1, float v2, float v3, float v4,
    float v5, float v6, float v7, float v8)
{
    const float ax = v0 - qx, ay = v1 - qy, az = v2 - qz;
    const float bx = v3 - qx, by = v4 - qy, bz = v5 - qz;
    const float cx = v6 - qx, cy = v7 - qy, cz = v8 - qz;

    const float ux = fmaf(by, cz, -bz * cy);
    const float uy = fmaf(bz, cx, -bx * cz);
    const float uz = fmaf(bx, cy, -by * cx);
    const float det = fmaf(ax, ux, fmaf(ay, uy, az * uz));

    const float na = __builtin_amdgcn_sqrtf(fmaf(ax, ax, fmaf(ay, ay, az * az)));
    const float nb = __builtin_amdgcn_sqrtf(fmaf(bx, bx, fmaf(by, by, bz * bz)));
    const float nc = __builtin_amdgcn_sqrtf(fmaf(cx, cx, fmaf(cy, cy, cz * cz)));

    const float ab = fmaf(ax, bx, fmaf(ay, by, az * bz));
    const float bc = fmaf(bx, cx, fmaf(by, cy, bz * cz));
    const float ac = fmaf(ax, cx, fmaf(ay, cy, az * cz));

    const float denom = fmaf(na * nb, nc, fmaf(bc, na, fmaf(ac, nb, ab * nc)));
    return fast_atan2f(det, denom);
}

// Partial-sum kernel: block (bx,by) handles queries [bx*QBLK, +QBLK) x faces
// [by*FT, +FT); writes disjoint partials to ws[by*N_Q + q]. No atomics.
__global__ __launch_bounds__(256) void winding_partial(
    const float* __restrict__ qp,   // [N_Q][3]
    const float* __restrict__ fc,   // [N_F][9]
    float* __restrict__ ws)         // [FSPLIT][N_Q]
{
    const int q0 = blockIdx.x * QBLK + threadIdx.x;
    const int q1 = q0 + 256, q2 = q0 + 512, q3 = q0 + 768;
    const int f0 = blockIdx.y * FT;

    const float q0x = qp[q0*3+0], q0y = qp[q0*3+1], q0z = qp[q0*3+2];
    const float q1x = qp[q1*3+0], q1y = qp[q1*3+1], q1z = qp[q1*3+2];
    const float q2x = qp[q2*3+0], q2y = qp[q2*3+1], q2z = qp[q2*3+2];
    const float q3x = qp[q3*3+0], q3y = qp[q3*3+1], q3z = qp[q3*3+2];

    float s0 = 0.0f, s1 = 0.0f, s2 = 0.0f, s3 = 0.0f;
    #pragma unroll 4
    for (int f = 0; f < FT; ++f) {
        // Wave-uniform address -> scalar loads; faces (144 KB) are L2-resident.
        const float* v = fc + (size_t)(f0 + f) * 9;
        const float v0 = v[0], v1 = v[1], v2 = v[2];
        const float v3 = v[3], v4 = v[4], v5 = v[5];
        const float v6 = v[6], v7 = v[7], v8 = v[8];

        s0 += pair_term(q0x, q0y, q0z, v0, v1, v2, v3, v4, v5, v6, v7, v8);
        s1 += pair_term(q1x, q1y, q1z, v0, v1, v2, v3, v4, v5, v6, v7, v8);
        s2 += pair_term(q2x, q2y, q2z, v0, v1, v2, v3, v4, v5, v6, v7, v8);
        s3 += pair_term(q3x, q3y, q3z, v0, v1, v2, v3, v4, v5, v6, v7, v8);
    }

    float* w = ws + (size_t)blockIdx.y * N_Q;
    w[q0] = s0; w[q1] = s1; w[q2] = s2; w[q3] = s3;
}

// Reduce: out[q] = (1/2pi) * sum_s ws[s][q]. Writes d_out exactly once.
__global__ __launch_bounds__(256) void winding_reduce(
    const float* __restrict__ ws, float* __restrict__ out)
{
    const int q = blockIdx.x * 256 + threadIdx.x;
    float a0 = 0.0f, a1 = 0.0f, a2 = 0.0f, a3 = 0.0f;
    #pragma unroll 4
    for (int s = 0; s < FSPLIT; s += 4) {
        a0 += ws[(size_t)(s+0) * N_Q + q];
        a1 += ws[(size_t)(s+1) * N_Q + q];
        a2 += ws[(size_t)(s+2) * N_Q + q];
        a3 += ws[(size_t)(s+3) * N_Q + q];
    }
    out[q] = ((a0 + a1) + (a2 + a3)) * INV_2PI;
}

// Fallback (ws too small): atomic accumulation into pre-zeroed out.
__global__ __launch_bounds__(256) void winding_atomic(
    const float* __restrict__ qp, const float* __restrict__ fc,
    float* __restrict__ out)
{
    const int q0 = blockIdx.x * QBLK + threadIdx.x;
    const int q1 = q0 + 256, q2 = q0 + 512, q3 = q0 + 768;
    const int f0 = blockIdx.y * FT;

    const float q0x = qp[q0*3+0], q0y = qp[q0*3+1], q0z = qp[q0*3+2];
    const float q1x = qp[q1*3+0], q1y = qp[q1*3+1], q1z = qp[q1*3+2];
    const float q2x = qp[q2*3+0], q2y = qp[q2*3+1], q2z = qp[q2*3+2];
    const float q3x = qp[q3*3+0], q3y = qp[q3*3+1], q3z = qp[q3*3+2];

    float s0 = 0.0f, s1 = 0.0f, s2 = 0.0f, s3 = 0.0f;
    #pragma unroll 4
    for (int f = 0; f < FT; ++f) {
        const float* v = fc + (size_t)(f0 + f) * 9;
        const float v0 = v[0], v1 = v[1], v2 = v[2];
        const float v3 = v[3], v4 = v[4], v5 = v[5];
        const float v6 = v[6], v7 = v[7], v8 = v[8];
        s0 += pair_term(q0x, q0y, q0z, v0, v1, v2, v3, v4, v5, v6, v7, v8);
        s1 += pair_term(q1x, q1y, q1z, v0, v1, v2, v3, v4, v5, v6, v7, v8);
        s2 += pair_term(q2x, q2y, q2z, v0, v1, v2, v3, v4, v5, v6, v7, v8);
        s3 += pair_term(q3x, q3y, q3z, v0, v1, v2, v3, v4, v5, v6, v7, v8);
    }
    atomicAdd(&out[q0], s0 * INV_2PI);
    atomicAdd(&out[q1], s1 * INV_2PI);
    atomicAdd(&out[q2], s2 * INV_2PI);
    atomicAdd(&out[q3], s3 * INV_2PI);
}

extern "C" void kernel_launch(void* const* d_in, const int* in_sizes, int n_in,
                              void* d_out, int out_size, void* d_ws, size_t ws_size,
                              hipStream_t stream) {
    const float* qp = (const float*)d_in[0];   // query_points (1,4096,3) f32
    const float* fc = (const float*)d_in[1];   // face_coord   (1,4096,3,3) f32
    float* out = (float*)d_out;                // (1,4096) f32

    const size_t ws_needed = (size_t)FSPLIT * N_Q * sizeof(float);
    dim3 grid(N_Q / QBLK, FSPLIT);
    dim3 block(256);

    if (ws_size >= ws_needed) {
        float* ws = (float*)d_ws;
        winding_partial<<<grid, block, 0, stream>>>(qp, fc, ws);
        winding_reduce<<<dim3(N_Q / 256), block, 0, stream>>>(ws, out);
    } else {
        // Fallback: pre-zero out (harness never re-poisons between replays),
        // then accumulate with device-scope atomics.
        hipMemsetAsync(out, 0, (size_t)out_size * sizeof(float), stream);
        winding_atomic<<<grid, block, 0, stream>>>(qp, fc, out);
    }
}

// Round 5
// 32.509 us; speedup vs baseline: 1.4420x; 1.4420x over previous
//
#include <hip/hip_runtime.h>
#include <math.h>

// B=1, N=4096 queries, F=4096 faces (fixed by reference setup_inputs).
#define N_Q 4096
#define N_F 4096
#define QPT 2                  // queries per thread; x unroll4 = 8 chains (no spill, proven R3)
#define QBLK (256 * QPT)       // 512 queries per block
#define FSPLIT 256             // 8 q-blocks x 256 f-splits = 2048 blocks = 8/CU = 32 waves/CU
#define FT (N_F / FSPLIT)      // 16 faces per block
#define INV_2PI 0.15915494309189535f

// Fast atan2: 6-coeff odd minimax poly on [0,1] (max err ~1e-5 rad),
// v_rcp_f32 division, quadrant fixup via selects.
__device__ __forceinline__ float fast_atan2f(float y, float x) {
    const float pi   = 3.14159265358979f;
    const float pi_2 = 1.57079632679490f;
    float ax = fabsf(x), ay = fabsf(y);
    float mx = fmaxf(ax, ay), mn = fminf(ax, ay);
    float t = mn * __builtin_amdgcn_rcpf(mx);      // t in [0,1]
    t = (mx == 0.0f) ? 0.0f : t;                   // atan2(0,0) -> 0 guard
    float s = t * t;
    float p =              -0.0117212f;
    p = fmaf(p, s,  0.05265332f);
    p = fmaf(p, s, -0.11643287f);
    p = fmaf(p, s,  0.19354346f);
    p = fmaf(p, s, -0.33262347f);
    p = fmaf(p, s,  0.99997726f);
    float r = p * t;                               // atan(t) on [0, pi/4]
    r = (ay > ax) ? (pi_2 - r) : r;                // octant -> quadrant I
    r = (x < 0.0f) ? (pi - r) : r;                 // quadrant II
    return copysignf(r, y);                        // lower half-plane
}

__device__ __forceinline__ float pair_term(
    float qx, float qy, float qz,
    float v0, float v1, float v2, float v3, float v4,
    float v5, float v6, float v7, float v8)
{
    const float ax = v0 - qx, ay = v1 - qy, az = v2 - qz;
    const float bx = v3 - qx, by = v4 - qy, bz = v5 - qz;
    const float cx = v6 - qx, cy = v7 - qy, cz = v8 - qz;

    const float ux = fmaf(by, cz, -bz * cy);
    const float uy = fmaf(bz, cx, -bx * cz);
    const float uz = fmaf(bx, cy, -by * cx);
    const float det = fmaf(ax, ux, fmaf(ay, uy, az * uz));

    const float na = __builtin_amdgcn_sqrtf(fmaf(ax, ax, fmaf(ay, ay, az * az)));
    const float nb = __builtin_amdgcn_sqrtf(fmaf(bx, bx, fmaf(by, by, bz * bz)));
    const float nc = __builtin_amdgcn_sqrtf(fmaf(cx, cx, fmaf(cy, cy, cz * cz)));

    const float ab = fmaf(ax, bx, fmaf(ay, by, az * bz));
    const float bc = fmaf(bx, cx, fmaf(by, cy, bz * cz));
    const float ac = fmaf(ax, cx, fmaf(ay, cy, az * cz));

    const float denom = fmaf(na * nb, nc, fmaf(bc, na, fmaf(ac, nb, ab * nc)));
    return fast_atan2f(det, denom);
}

__global__ __launch_bounds__(256) void winding_kernel(
    const float* __restrict__ qp,   // [N_Q][3]
    const float* __restrict__ fc,   // [N_F][9]
    float* __restrict__ out)        // [N_Q]
{
    const int q0 = blockIdx.x * QBLK + threadIdx.x;  // query 0
    const int q1 = q0 + 256;                         // query 1
    const int f0 = blockIdx.y * FT;                  // this block's face slice

    const float q0x = qp[q0*3+0], q0y = qp[q0*3+1], q0z = qp[q0*3+2];
    const float q1x = qp[q1*3+0], q1y = qp[q1*3+1], q1z = qp[q1*3+2];

    float s0 = 0.0f, s1 = 0.0f;
    #pragma unroll 4
    for (int f = 0; f < FT; ++f) {
        // Wave-uniform address -> scalar s_load on the SALU pipe;
        // faces (144 KB) are L2-resident.
        const float* v = fc + (size_t)(f0 + f) * 9;
        const float v0 = v[0], v1 = v[1], v2 = v[2];
        const float v3 = v[3], v4 = v[4], v5 = v[5];
        const float v6 = v[6], v7 = v[7], v8 = v[8];

        s0 += pair_term(q0x, q0y, q0z, v0, v1, v2, v3, v4, v5, v6, v7, v8);
        s1 += pair_term(q1x, q1y, q1z, v0, v1, v2, v3, v4, v5, v6, v7, v8);
    }

    atomicAdd(&out[q0], s0 * INV_2PI);
    atomicAdd(&out[q1], s1 * INV_2PI);
}

extern "C" void kernel_launch(void* const* d_in, const int* in_sizes, int n_in,
                              void* d_out, int out_size, void* d_ws, size_t ws_size,
                              hipStream_t stream) {
    const float* qp = (const float*)d_in[0];   // query_points (1,4096,3) f32
    const float* fc = (const float*)d_in[1];   // face_coord   (1,4096,3,3) f32
    float* out = (float*)d_out;                // (1,4096) f32

    // Harness poisons d_out once and never re-poisons between replays:
    // we accumulate with atomics, so zero it ourselves every call.
    hipMemsetAsync(out, 0, (size_t)out_size * sizeof(float), stream);

    dim3 grid(N_Q / QBLK, FSPLIT);
    dim3 block(256);
    winding_kernel<<<grid, block, 0, stream>>>(qp, fc, out);
}

// Round 6
// 28.643 us; speedup vs baseline: 1.6366x; 1.1350x over previous
//
#include <hip/hip_runtime.h>
#include <math.h>

// B=1, N=4096 queries, F=4096 faces (fixed by reference setup_inputs).
#define N_Q 4096
#define N_F 4096
#define QPT 2                  // queries per thread
#define QBLK (256 * QPT)       // 512 queries per block
#define FSPLIT 128             // 8 q-blocks x 128 f-splits = 1024 blocks (4/CU)
#define FT (N_F / FSPLIT)      // 32 faces per block
#define INV_2PI 0.15915494309189535f

// Fast atan2: 6-coeff odd minimax poly on [0,1] (max err ~1e-5 rad),
// v_rcp_f32 division, quadrant fixup via selects. ~19 VALU + 1 trans.
__device__ __forceinline__ float fast_atan2f(float y, float x) {
    const float pi   = 3.14159265358979f;
    const float pi_2 = 1.57079632679490f;
    float ax = fabsf(x), ay = fabsf(y);
    float mx = fmaxf(ax, ay), mn = fminf(ax, ay);
    mx = fmaxf(mx, 1e-30f);                        // 0/0 -> 0, no NaN
    float t = mn * __builtin_amdgcn_rcpf(mx);      // t in [0,1]
    float s = t * t;
    float p =              -0.0117212f;
    p = fmaf(p, s,  0.05265332f);
    p = fmaf(p, s, -0.11643287f);
    p = fmaf(p, s,  0.19354346f);
    p = fmaf(p, s, -0.33262347f);
    p = fmaf(p, s,  0.99997726f);
    float r = p * t;                               // atan(t) on [0, pi/4]
    r = (ay > ax) ? (pi_2 - r) : r;                // octant -> quadrant I
    r = (x < 0.0f) ? (pi - r) : r;                 // quadrant II
    return copysignf(r, y);                        // lower half-plane
}

// Per-pair term from precomputed face constants:
//   A=(a, |a|^2)  B=(b, |b|^2)  C=(c, |c|^2)  Nv=(n, D)  K=(a.b, b.c, a.c, -)
//   th = |q|^2 / 2
// d'_x = th - q.x ;  |x-q|^2 = Px + 2 d'_x ;  (x-q).(y-q) = Kxy + d'_x + d'_y
// det[a-q,b-q,c-q] = D - q.n   with  n = bxc + cxa + axb.
__device__ __forceinline__ float pair_term(
    float qx, float qy, float qz, float th,
    float4 A, float4 B, float4 C, float4 Nv, float4 K)
{
    const float da  = fmaf(-qx, A.x, fmaf(-qy, A.y, fmaf(-qz, A.z, th)));
    const float db  = fmaf(-qx, B.x, fmaf(-qy, B.y, fmaf(-qz, B.z, th)));
    const float dc  = fmaf(-qx, C.x, fmaf(-qy, C.y, fmaf(-qz, C.z, th)));
    const float det = fmaf(-qx, Nv.x, fmaf(-qy, Nv.y, fmaf(-qz, Nv.z, Nv.w)));

    const float na = __builtin_amdgcn_sqrtf(fmaf(2.0f, da, A.w));
    const float nb = __builtin_amdgcn_sqrtf(fmaf(2.0f, db, B.w));
    const float nc = __builtin_amdgcn_sqrtf(fmaf(2.0f, dc, C.w));

    const float ab = K.x + (da + db);
    const float bc = K.y + (db + dc);
    const float ac = K.z + (da + dc);

    const float denom = fmaf(na * nb, nc, fmaf(bc, na, fmaf(ac, nb, ab * nc)));
    return fast_atan2f(det, denom);
}

__global__ __launch_bounds__(256) void winding_kernel(
    const float* __restrict__ qp,   // [N_Q][3]
    const float* __restrict__ fc,   // [N_F][9]
    float* __restrict__ out)        // [N_Q]
{
    __shared__ float  raw[FT * 9];      // staged raw face data
    __shared__ float4 cst[FT][5];       // per-face constants

    const int tid = threadIdx.x;

    // Stage this block's face slice (FT*9 = 288 dwords, coalesced).
    for (int i = tid; i < FT * 9; i += 256)
        raw[i] = fc[(size_t)blockIdx.y * FT * 9 + i];
    __syncthreads();

    // Threads 0..FT-1 each compute one face's constants (cost amortized
    // over 512 queries x FT faces of main-loop work).
    if (tid < FT) {
        const float* v = &raw[tid * 9];
        const float ax = v[0], ay = v[1], az = v[2];
        const float bx = v[3], by = v[4], bz = v[5];
        const float cx = v[6], cy = v[7], cz = v[8];
        const float ux = by*cz - bz*cy, uy = bz*cx - bx*cz, uz = bx*cy - by*cx; // bxc
        const float vx = cy*az - cz*ay, vy = cz*ax - cx*az, vz = cx*ay - cy*ax; // cxa
        const float wx = ay*bz - az*by, wy = az*bx - ax*bz, wz = ax*by - ay*bx; // axb
        const float D  = ax*ux + ay*uy + az*uz;
        cst[tid][0] = make_float4(ax, ay, az, ax*ax + ay*ay + az*az);
        cst[tid][1] = make_float4(bx, by, bz, bx*bx + by*by + bz*bz);
        cst[tid][2] = make_float4(cx, cy, cz, cx*cx + cy*cy + cz*cz);
        cst[tid][3] = make_float4(ux + vx + wx, uy + vy + wy, uz + vz + wz, D);
        cst[tid][4] = make_float4(ax*bx + ay*by + az*bz,
                                  bx*cx + by*cy + bz*cz,
                                  ax*cx + ay*cy + az*cz, 0.0f);
    }
    __syncthreads();

    const int q0 = blockIdx.x * QBLK + tid;
    const int q1 = q0 + 256;
    const float q0x = qp[q0*3+0], q0y = qp[q0*3+1], q0z = qp[q0*3+2];
    const float q1x = qp[q1*3+0], q1y = qp[q1*3+1], q1z = qp[q1*3+2];
    const float th0 = 0.5f * fmaf(q0x, q0x, fmaf(q0y, q0y, q0z * q0z));
    const float th1 = 0.5f * fmaf(q1x, q1x, fmaf(q1y, q1y, q1z * q1z));

    float s0 = 0.0f, s1 = 0.0f;
    #pragma unroll 4
    for (int f = 0; f < FT; ++f) {
        // Uniform-address LDS reads -> broadcast, no bank conflicts.
        const float4 A  = cst[f][0];
        const float4 B  = cst[f][1];
        const float4 C  = cst[f][2];
        const float4 Nv = cst[f][3];
        const float4 K  = cst[f][4];
        s0 += pair_term(q0x, q0y, q0z, th0, A, B, C, Nv, K);
        s1 += pair_term(q1x, q1y, q1z, th1, A, B, C, Nv, K);
    }

    atomicAdd(&out[q0], s0 * INV_2PI);
    atomicAdd(&out[q1], s1 * INV_2PI);
}

extern "C" void kernel_launch(void* const* d_in, const int* in_sizes, int n_in,
                              void* d_out, int out_size, void* d_ws, size_t ws_size,
                              hipStream_t stream) {
    const float* qp = (const float*)d_in[0];   // query_points (1,4096,3) f32
    const float* fc = (const float*)d_in[1];   // face_coord   (1,4096,3,3) f32
    float* out = (float*)d_out;                // (1,4096) f32

    // Harness poisons d_out once and never re-poisons between replays:
    // we accumulate with atomics, so zero it ourselves every call.
    hipMemsetAsync(out, 0, (size_t)out_size * sizeof(float), stream);

    dim3 grid(N_Q / QBLK, FSPLIT);
    dim3 block(256);
    winding_kernel<<<grid, block, 0, stream>>>(qp, fc, out);
}